// Round 1
// baseline (335.717 us; speedup 1.0000x reference)
//
#include <hip/hip_runtime.h>

// SSIM loss, fused single pass, barrier-free, spill-free.
// [32,3,512,512] fp32 = 96 planes of 512x512. Each WAVE owns a 64x64 tile.
// Round-6: EXACT round-3 arithmetic (verified, absmax 3.9e-3) +
//  - global_load_lds (4B/lane) into a 4-deep per-wave LDS ring
//  - prefetch distance 3 rows, counted s_waitcnt vmcnt(12) (never 0)
//  - column-OOB lanes exec-masked; their LDS slots pre-zeroed once
//  - row-OOB phases: wave-uniform skip of conv+scatter (== conv of zeros)
// Theory: round-5 at 285.9us was latency-bound (VALU floor ~51us, HBM floor
// ~41us): 1-phase prefetch distance (~264cy) << HBM latency (~900cy).

#define IMG_H   512
#define IMG_W   512
#define TH      64          // tile rows/cols per wave
#define NCHUNK  7           // 7*11 = 77 row-phases (74 input rows needed)
#define LROW    80          // floats per LDS row-slot (74 used)
#define SSIM_C1 1e-4f
#define SSIM_C2 9e-4f

// Gaussian taps, sigma=1.5, window 11.
__device__ constexpr float G[11] = {
    0.00102838f, 0.00759879f, 0.03600078f, 0.10936070f, 0.21300563f,
    0.26601180f,
    0.21300563f, 0.10936070f, 0.03600078f, 0.00759879f, 0.00102838f
};

// Async 4B/lane global->LDS. LDS dest semantics: wave-uniform base + lane*4
// (m104/m173), so we always pass the slot-0 (or slot-64) base pointer;
// exec-masked lanes simply don't write (their slots stay pre-zeroed).
__device__ __forceinline__ void gload4(const float* g, float* l) {
    __builtin_amdgcn_global_load_lds(
        (const __attribute__((address_space(1))) float*)g,
        (__attribute__((address_space(3))) float*)l, 4, 0, 0);
}

template<int PH>
__device__ __forceinline__ void phase(const float* __restrict__ ppl,
                                      const float* __restrict__ tpl,
                                      int r0, int j0, int rb4,
                                      float (*Bp)[LROW], float (*Bt)[LROW],
                                      int lane, int cm, int ch,
                                      bool cmok, bool chok,
                                      float (&acc)[11][5], float& lsum) {
    const int j = j0 + PH;

    // ---- issue async loads for row j+3 into ring slot (j+3)&3 ----
    // Row index clamped so EVERY phase issues exactly 4 VMEM ops (vmcnt
    // arithmetic stays exact); clamped-row garbage is never read because
    // row-OOB phases skip the conv below.
    {
        const int rg  = r0 - 5 + j + 3;
        const int rgc = min(max(rg, 0), IMG_H - 1);
        const size_t ro = (size_t)rgc * IMG_W;
        const int sI = (rb4 + PH + 3) & 3;
        if (cmok) {                       // never all-false: exec != 0
            gload4(ppl + ro + cm, &Bp[sI][0]);
            gload4(tpl + ro + cm, &Bt[sI][0]);
        }
        if (chok) {                       // never all-false: exec != 0
            gload4(ppl + ro + ch, &Bp[sI][64]);
            gload4(tpl + ro + ch, &Bt[sI][64]);
        }
    }

    // ---- counted wait: rows j+1..j+3 (12 loads) may stay in flight ----
    asm volatile("s_waitcnt vmcnt(12)" ::: "memory");

    // ---- horizontal 11-tap conv of p,t,p^2,t^2,pt + vertical scatter ----
    const int rgj = r0 - 5 + j;
    if (rgj >= 0 && rgj < IMG_H) {        // wave-uniform (r0, j uniform)
        const int sR = (rb4 + PH) & 3;
        const float* Lp = Bp[sR];
        const float* Lt = Bt[sR];
        float hp = 0.f, ht = 0.f, hpp = 0.f, htt = 0.f, hpt = 0.f;
        #pragma unroll
        for (int k = 0; k < 11; ++k) {
            const float w = G[k];
            const float x = Lp[lane + k];
            const float y = Lt[lane + k];
            hp  = fmaf(w, x, hp);
            ht  = fmaf(w, y, ht);
            const float wa = w * x;
            hpp = fmaf(wa, x, hpp);
            hpt = fmaf(wa, y, hpt);
            const float wb = w * y;
            htt = fmaf(wb, y, htt);
        }
        // vertical scatter: row j feeds outputs l = j-10..j, slot = l%11
#define SCAT(s) { constexpr int m = ((s) - PH + 21) % 11;                    \
                  constexpr float w = G[10 - m];                             \
                  acc[s][0] = fmaf(w, hp,  acc[s][0]);                       \
                  acc[s][1] = fmaf(w, ht,  acc[s][1]);                       \
                  acc[s][2] = fmaf(w, hpp, acc[s][2]);                       \
                  acc[s][3] = fmaf(w, htt, acc[s][3]);                       \
                  acc[s][4] = fmaf(w, hpt, acc[s][4]); }
        SCAT(0) SCAT(1) SCAT(2) SCAT(3) SCAT(4) SCAT(5)
        SCAT(6) SCAT(7) SCAT(8) SCAT(9) SCAT(10)
#undef SCAT
    }
    // (row-OOB: conv of zero-filled rows contributes zero -> skipping the
    //  reads AND the scatter is arithmetically identical to round-3/5.)

    // ---- emit completed output row l = j-10 (slot (PH+1)%11), then reset ----
    constexpr int SE = (PH + 1) % 11;
    const int l = j - 10;
    if (l >= 0 && l < TH) {                       // wave-uniform branch
        const float mp = acc[SE][0], mt = acc[SE][1];
        const float mpp = mp * mp, mtt = mt * mt, mpt = mp * mt;
        const float sp  = acc[SE][2] - mpp;
        const float st  = acc[SE][3] - mtt;
        const float spt = acc[SE][4] - mpt;
        const float num = (2.f * mpt + SSIM_C1) * (2.f * spt + SSIM_C2);
        const float den = (mpp + mtt + SSIM_C1) * (sp + st + SSIM_C2);
        lsum += num * __builtin_amdgcn_rcpf(den); // den >= C1*C2 > 0
    }
    acc[SE][0] = 0.f; acc[SE][1] = 0.f; acc[SE][2] = 0.f;
    acc[SE][3] = 0.f; acc[SE][4] = 0.f;
}

__global__ __launch_bounds__(256, 4) void ssim_main(const float* __restrict__ pred,
                                                    const float* __restrict__ targ,
                                                    float* __restrict__ ws) {
    __shared__ float Bp[4][4][LROW];   // [wave][ringbuf][slot] pred  = 5.1 KB
    __shared__ float Bt[4][4][LROW];   // [wave][ringbuf][slot] targ  = 5.1 KB
    __shared__ float wsum[4];

    const int tid  = threadIdx.x;
    const int lane = tid & 63;
    const int wid  = tid >> 6;

    // 6144 tiles = 8 col-strips x 8 row-bands x 96 planes; 4 waves/block.
    const int gt    = __builtin_amdgcn_readfirstlane(blockIdx.x * 4 + wid);
    const int c0    = (gt & 7) * TH;
    const int r0    = ((gt >> 3) & 7) * TH;
    const int plane = gt >> 6;
    const float* ppl = pred + (size_t)plane * (IMG_H * IMG_W);
    const float* tpl = targ + (size_t)plane * (IMG_H * IMG_W);

    float (*Wp)[LROW] = Bp[wid];
    float (*Wt)[LROW] = Bt[wid];

    const int  cm   = c0 - 5 + lane;              // main load column
    const int  ch   = c0 + 59 + lane;             // halo load column (lane<10)
    const bool cmok = (cm >= 0) && (cm < IMG_W);
    const bool chok = (lane < 10) && (ch < IMG_W);

    // Pre-zero LDS slots of permanently exec-masked lanes (loop-invariant:
    // cmok/chok don't depend on the row) in all 4 ring buffers. gload_lds
    // never touches these slots, so they stay zero for the whole kernel.
    if (!cmok) {
        #pragma unroll
        for (int b = 0; b < 4; ++b) { Wp[b][lane] = 0.f; Wt[b][lane] = 0.f; }
    }
    if (lane < 10 && !chok) {
        #pragma unroll
        for (int b = 0; b < 4; ++b) { Wp[b][64 + lane] = 0.f; Wt[b][64 + lane] = 0.f; }
    }

    // Prologue: issue rows 0,1,2 into ring slots 0,1,2 (12 VMEM ops).
    #pragma unroll
    for (int r = 0; r < 3; ++r) {
        const int rg  = max(r0 - 5 + r, 0);       // upper bound safe (<=445)
        const size_t ro = (size_t)rg * IMG_W;
        if (cmok) {
            gload4(ppl + ro + cm, &Wp[r][0]);
            gload4(tpl + ro + cm, &Wt[r][0]);
        }
        if (chok) {
            gload4(ppl + ro + ch, &Wp[r][64]);
            gload4(tpl + ro + ch, &Wt[r][64]);
        }
    }

    float acc[11][5];
    #pragma unroll
    for (int s = 0; s < 11; ++s) {
        acc[s][0] = 0.f; acc[s][1] = 0.f; acc[s][2] = 0.f;
        acc[s][3] = 0.f; acc[s][4] = 0.f;
    }

    float lsum = 0.f;

    for (int chunk = 0; chunk < NCHUNK; ++chunk) {
        const int j0  = chunk * 11;
        const int rb4 = j0 & 3;                   // ring phase of this chunk
#define P(n) phase<n>(ppl, tpl, r0, j0, rb4, Wp, Wt, \
                      lane, cm, ch, cmok, chok, acc, lsum);
        P(0) P(1) P(2) P(3) P(4) P(5) P(6) P(7) P(8) P(9) P(10)
#undef P
    }

    // wave reduce -> one plain store per block into the workspace
    #pragma unroll
    for (int off = 32; off > 0; off >>= 1) lsum += __shfl_down(lsum, off);
    if (lane == 0) wsum[wid] = lsum;
    __syncthreads();
    if (tid == 0) ws[blockIdx.x] = wsum[0] + wsum[1] + wsum[2] + wsum[3];
}

__global__ __launch_bounds__(256) void ssim_finalize(const float* __restrict__ ws,
                                                     float* __restrict__ out) {
    __shared__ float wsum[4];
    const int tid  = threadIdx.x;
    const int lane = tid & 63;
    const int wid  = tid >> 6;
    float s = 0.f;
    #pragma unroll
    for (int i = 0; i < 6; ++i) s += ws[tid + 256 * i];   // 1536 = 6*256
    #pragma unroll
    for (int off = 32; off > 0; off >>= 1) s += __shfl_down(s, off);
    if (lane == 0) wsum[wid] = s;
    __syncthreads();
    if (tid == 0) {
        const float tot = wsum[0] + wsum[1] + wsum[2] + wsum[3];
        out[0] = 1.0f - tot * (1.0f / 25165824.0f);  // 1 - sum/(32*3*512*512)
    }
}

extern "C" void kernel_launch(void* const* d_in, const int* in_sizes, int n_in,
                              void* d_out, int out_size, void* d_ws, size_t ws_size,
                              hipStream_t stream) {
    (void)in_sizes; (void)n_in; (void)out_size; (void)ws_size;
    const float* pred = (const float*)d_in[0];
    const float* targ = (const float*)d_in[1];
    float* ws  = (float*)d_ws;          // 1536 floats of scratch
    float* out = (float*)d_out;

    ssim_main<<<dim3(1536), 256, 0, stream>>>(pred, targ, ws);
    ssim_finalize<<<1, 256, 0, stream>>>(ws, out);
}

// Round 3
// 270.453 us; speedup vs baseline: 1.2413x; 1.2413x over previous
//
#include <hip/hip_runtime.h>

// SSIM loss, fused single pass, barrier-free, spill-free.
// [32,3,512,512] fp32 = 96 planes of 512x512. Each WAVE owns a 64x64 tile.
// Round-8: round-7 structure with the addressing BUG FIXED:
//   global_load_lds global source addr is PER-LANE (only the LDS dest gets
//   +lane*16 automatically). Round-7 passed a wave-uniform pointer -> every
//   lane read the same 16B (wrong data) and at c0=0,row=0 it read pred-8
//   (OOB -> device abort). Fix: gload16(ps + 4*lane, ...).
// Structure (from round-7):
//  - global_load_lds dwordx4 (16B/lane, 18-20 active lanes): 2 VMEM/phase
//  - 8-slot LDS ring, prefetch distance 5 rows, s_waitcnt vmcnt(10) (never 0)
//  - uniform row base (SALU) + invariant voffset=lane*16 (saddr form)
//  - aligned load window [c0-8, c0+72); conv reads L[lane+3+k]
//  - EXACT round-3 arithmetic (round-6 verified absmax 0.0)

#define IMG_H   512
#define IMG_W   512
#define TH      64          // tile rows/cols per wave
#define NCHUNK  7           // 7*11 = 77 row-phases (74 input rows needed)
#define LROW    80          // floats per LDS row-slot (window is 80 cols)
#define RING    8           // ring slots (rows j..j+5 live)
#define SSIM_C1 1e-4f
#define SSIM_C2 9e-4f

// Gaussian taps, sigma=1.5, window 11.
__device__ constexpr float G[11] = {
    0.00102838f, 0.00759879f, 0.03600078f, 0.10936070f, 0.21300563f,
    0.26601180f,
    0.21300563f, 0.10936070f, 0.03600078f, 0.00759879f, 0.00102838f
};

// Async 16B/lane global->LDS. Global addr is per-lane; LDS dest is
// wave-uniform base + lane*16 (m97/m104).
__device__ __forceinline__ void gload16(const float* g, float* l) {
    __builtin_amdgcn_global_load_lds(
        (const __attribute__((address_space(1))) float*)g,
        (__attribute__((address_space(3))) float*)l, 16, 0, 0);
}

template<int PH>
__device__ __forceinline__ void phase(const float* __restrict__ pplw,
                                      const float* __restrict__ tplw,
                                      int r0, int j0, int lane4,
                                      float (*Bp)[LROW], float (*Bt)[LROW],
                                      int lane, bool lv,
                                      float (&acc)[11][5], float& lsum) {
    const int j = j0 + PH;

    // ---- issue async dwordx4 loads for row j+5 into ring slot (j+5)&7 ----
    // Row clamped so EVERY phase issues exactly 2 VMEM ops (vmcnt arithmetic
    // exact); clamped-row garbage never read (row-OOB phases skip conv).
    {
        const int rg  = r0 + j;                   // = (r0-5) + (j+5)
        const int rgc = min(max(rg, 0), IMG_H - 1);
        const int sI  = (j + 5) & (RING - 1);
        const float* ps = pplw + (size_t)rgc * IMG_W + lane4;  // per-lane!
        const float* ts = tplw + (size_t)rgc * IMG_W + lane4;
        if (lv) {                                 // 18-20 lanes active
            gload16(ps, &Bp[sI][0]);
            gload16(ts, &Bt[sI][0]);
        }
    }

    // ---- counted wait: rows j+1..j+5 (10 loads) may stay in flight ----
    asm volatile("s_waitcnt vmcnt(10)" ::: "memory");

    // ---- horizontal 11-tap conv of p,t,p^2,t^2,pt + vertical scatter ----
    const int rgj = r0 - 5 + j;
    if (rgj >= 0 && rgj < IMG_H) {        // wave-uniform (r0, j uniform)
        const int sR = j & (RING - 1);
        const float* Lp = Bp[sR];
        const float* Lt = Bt[sR];
        float hp = 0.f, ht = 0.f, hpp = 0.f, htt = 0.f, hpt = 0.f;
        #pragma unroll
        for (int k = 0; k < 11; ++k) {
            const float w = G[k];
            const float x = Lp[lane + 3 + k];
            const float y = Lt[lane + 3 + k];
            hp  = fmaf(w, x, hp);
            ht  = fmaf(w, y, ht);
            const float wa = w * x;
            hpp = fmaf(wa, x, hpp);
            hpt = fmaf(wa, y, hpt);
            const float wb = w * y;
            htt = fmaf(wb, y, htt);
        }
        // vertical scatter: row j feeds outputs l = j-10..j, slot = l%11
#define SCAT(s) { constexpr int m = ((s) - PH + 21) % 11;                    \
                  constexpr float w = G[10 - m];                             \
                  acc[s][0] = fmaf(w, hp,  acc[s][0]);                       \
                  acc[s][1] = fmaf(w, ht,  acc[s][1]);                       \
                  acc[s][2] = fmaf(w, hpp, acc[s][2]);                       \
                  acc[s][3] = fmaf(w, htt, acc[s][3]);                       \
                  acc[s][4] = fmaf(w, hpt, acc[s][4]); }
        SCAT(0) SCAT(1) SCAT(2) SCAT(3) SCAT(4) SCAT(5)
        SCAT(6) SCAT(7) SCAT(8) SCAT(9) SCAT(10)
#undef SCAT
    }
    // (row-OOB: conv of zero rows contributes zero -> skip is identical.)

    // ---- emit completed output row l = j-10 (slot (PH+1)%11), then reset ----
    constexpr int SE = (PH + 1) % 11;
    const int l = j - 10;
    if (l >= 0 && l < TH) {                       // wave-uniform branch
        const float mp = acc[SE][0], mt = acc[SE][1];
        const float mpp = mp * mp, mtt = mt * mt, mpt = mp * mt;
        const float sp  = acc[SE][2] - mpp;
        const float st  = acc[SE][3] - mtt;
        const float spt = acc[SE][4] - mpt;
        const float num = (2.f * mpt + SSIM_C1) * (2.f * spt + SSIM_C2);
        const float den = (mpp + mtt + SSIM_C1) * (sp + st + SSIM_C2);
        lsum += num * __builtin_amdgcn_rcpf(den); // den >= C1*C2 > 0
    }
    acc[SE][0] = 0.f; acc[SE][1] = 0.f; acc[SE][2] = 0.f;
    acc[SE][3] = 0.f; acc[SE][4] = 0.f;
}

__global__ __launch_bounds__(256, 4) void ssim_main(const float* __restrict__ pred,
                                                    const float* __restrict__ targ,
                                                    float* __restrict__ ws) {
    __shared__ float Bp[4][RING][LROW];   // [wave][slot][col] pred  = 10.2 KB
    __shared__ float Bt[4][RING][LROW];   // [wave][slot][col] targ  = 10.2 KB
    __shared__ float wsum[4];

    const int tid  = threadIdx.x;
    const int lane = tid & 63;
    const int wid  = tid >> 6;

    // 6144 tiles = 8 col-strips x 8 row-bands x 96 planes; 4 waves/block.
    const int gt    = __builtin_amdgcn_readfirstlane(blockIdx.x * 4 + wid);
    const int c0    = (gt & 7) * TH;
    const int r0    = ((gt >> 3) & 7) * TH;
    const int plane = gt >> 6;
    // Window base: column c0-8 (16B-aligned since c0%64==0).
    const float* pplw = pred + (size_t)plane * (IMG_H * IMG_W) + (c0 - 8);
    const float* tplw = targ + (size_t)plane * (IMG_H * IMG_W) + (c0 - 8);

    float (*Wp)[LROW] = Bp[wid];
    float (*Wt)[LROW] = Bt[wid];

    // Lane lane covers window cols [4*lane, 4*lane+3] = global
    // [c0-8+4*lane, +3].
    const int  lane4 = lane * 4;
    const int  gc0   = c0 - 8 + lane4;
    const bool lv    = (lane < 20) && (gc0 >= 0) && (gc0 <= IMG_W - 4);

    // Pre-zero LDS words of permanently masked lanes (edge strips only):
    // gload_lds never touches them, so they stay zero all kernel.
    if (lane < 20 && !lv) {
        #pragma unroll
        for (int s = 0; s < RING; ++s) {
            #pragma unroll
            for (int w = 0; w < 4; ++w) {
                Wp[s][lane4 + w] = 0.f;
                Wt[s][lane4 + w] = 0.f;
            }
        }
    }

    // Prologue: issue rows j=0..4 (global rows r0-5..r0-1, clamped) into
    // ring slots 0..4 = 10 VMEM ops.
    #pragma unroll
    for (int r = 0; r < 5; ++r) {
        const int rg  = max(r0 - 5 + r, 0);       // top clamp only (r0<=448)
        const float* ps = pplw + (size_t)rg * IMG_W + lane4;
        const float* ts = tplw + (size_t)rg * IMG_W + lane4;
        if (lv) {
            gload16(ps, &Wp[r][0]);
            gload16(ts, &Wt[r][0]);
        }
    }

    float acc[11][5];
    #pragma unroll
    for (int s = 0; s < 11; ++s) {
        acc[s][0] = 0.f; acc[s][1] = 0.f; acc[s][2] = 0.f;
        acc[s][3] = 0.f; acc[s][4] = 0.f;
    }

    float lsum = 0.f;

    for (int chunk = 0; chunk < NCHUNK; ++chunk) {
        const int j0 = chunk * 11;
#define P(n) phase<n>(pplw, tplw, r0, j0, lane4, Wp, Wt, lane, lv, acc, lsum);
        P(0) P(1) P(2) P(3) P(4) P(5) P(6) P(7) P(8) P(9) P(10)
#undef P
    }

    // wave reduce -> one plain store per block into the workspace
    #pragma unroll
    for (int off = 32; off > 0; off >>= 1) lsum += __shfl_down(lsum, off);
    if (lane == 0) wsum[wid] = lsum;
    __syncthreads();
    if (tid == 0) ws[blockIdx.x] = wsum[0] + wsum[1] + wsum[2] + wsum[3];
}

__global__ __launch_bounds__(256) void ssim_finalize(const float* __restrict__ ws,
                                                     float* __restrict__ out) {
    __shared__ float wsum[4];
    const int tid  = threadIdx.x;
    const int lane = tid & 63;
    const int wid  = tid >> 6;
    float s = 0.f;
    #pragma unroll
    for (int i = 0; i < 6; ++i) s += ws[tid + 256 * i];   // 1536 = 6*256
    #pragma unroll
    for (int off = 32; off > 0; off >>= 1) s += __shfl_down(s, off);
    if (lane == 0) wsum[wid] = s;
    __syncthreads();
    if (tid == 0) {
        const float tot = wsum[0] + wsum[1] + wsum[2] + wsum[3];
        out[0] = 1.0f - tot * (1.0f / 25165824.0f);  // 1 - sum/(32*3*512*512)
    }
}

extern "C" void kernel_launch(void* const* d_in, const int* in_sizes, int n_in,
                              void* d_out, int out_size, void* d_ws, size_t ws_size,
                              hipStream_t stream) {
    (void)in_sizes; (void)n_in; (void)out_size; (void)ws_size;
    const float* pred = (const float*)d_in[0];
    const float* targ = (const float*)d_in[1];
    float* ws  = (float*)d_ws;          // 1536 floats of scratch
    float* out = (float*)d_out;

    ssim_main<<<dim3(1536), 256, 0, stream>>>(pred, targ, ws);
    ssim_finalize<<<1, 256, 0, stream>>>(ws, out);
}

// Round 5
// 253.613 us; speedup vs baseline: 1.3237x; 1.0664x over previous
//
#include <hip/hip_runtime.h>

// SSIM loss, fused single pass, barrier-free, spill-free.
// [32,3,512,512] fp32 = 96 planes of 512x512. Each WAVE owns a 64x64 tile.
// Round-10 == round-9 resubmitted (round-4 bench was an infra failure:
// "container failed twice", kernel never ran; same as round-0's false alarm).
// Round-9: round-8 structure (verified absmax 0.0, main 135us, VALUBusy 80%)
// + packed dual-f32 math to cut the VALU issue count ~40%:
//  - v_pk_fma_f32/v_pk_mul_f32 via ext_vector_type(2) + elementwise_fma:
//      conv tap: pk_fma(hp,ht) + pk_mul(wa,wb) + pk_fma(hpp,htt) + fma(hpt)
//                = 4 inst vs 7 scalar
//      scatter:  2 pk_fma + 1 fma per slot = 3 inst vs 5
//  - merged LDS buffer: p at [0..79], t at [80..159] of one row-slot ->
//    per-tap pair of reads shares one base -> ds_read2_b32 (11 vs 22 issues)
//  - packed fma is IEEE-identical per half, accumulation order unchanged
//    -> bit-exact vs round-8.
// Unchanged: 8-slot ring, distance-5 prefetch, s_waitcnt vmcnt(10) (never 0),
// per-lane global addr + uniform LDS dest, edge-lane pre-zeroed slots,
// EXACT round-3 arithmetic.

#define IMG_H   512
#define IMG_W   512
#define TH      64          // tile rows/cols per wave
#define NCHUNK  7           // 7*11 = 77 row-phases (74 input rows needed)
#define LROW    160         // floats per LDS row-slot: p[0..79] | t[80..159]
#define RING    8           // ring slots (rows j..j+5 live)
#define SSIM_C1 1e-4f
#define SSIM_C2 9e-4f

typedef float v2f __attribute__((ext_vector_type(2)));

// Gaussian taps, sigma=1.5, window 11.
__device__ constexpr float G[11] = {
    0.00102838f, 0.00759879f, 0.03600078f, 0.10936070f, 0.21300563f,
    0.26601180f,
    0.21300563f, 0.10936070f, 0.03600078f, 0.00759879f, 0.00102838f
};

// Async 16B/lane global->LDS. Global addr is per-lane; LDS dest is
// wave-uniform base + lane*16 (m97/m104).
__device__ __forceinline__ void gload16(const float* g, float* l) {
    __builtin_amdgcn_global_load_lds(
        (const __attribute__((address_space(1))) float*)g,
        (__attribute__((address_space(3))) float*)l, 16, 0, 0);
}

template<int PH>
__device__ __forceinline__ void phase(const float* __restrict__ pplw,
                                      const float* __restrict__ tplw,
                                      int r0, int j0, int lane4,
                                      float (*B)[LROW],
                                      int lane, bool lv,
                                      v2f (&acc01)[11], v2f (&acc23)[11],
                                      float (&accpt)[11], float& lsum) {
    const int j = j0 + PH;

    // ---- issue async dwordx4 loads for row j+5 into ring slot (j+5)&7 ----
    // Row clamped so EVERY phase issues exactly 2 VMEM ops (vmcnt arithmetic
    // exact); clamped-row garbage never read (row-OOB phases skip conv).
    {
        const int rg  = r0 + j;                   // = (r0-5) + (j+5)
        const int rgc = min(max(rg, 0), IMG_H - 1);
        const int sI  = (j + 5) & (RING - 1);
        const float* ps = pplw + (size_t)rgc * IMG_W + lane4;  // per-lane
        const float* ts = tplw + (size_t)rgc * IMG_W + lane4;
        if (lv) {                                 // 18-20 lanes active
            gload16(ps, &B[sI][0]);               // p -> [0..79]
            gload16(ts, &B[sI][80]);              // t -> [80..159]
        }
    }

    // ---- counted wait: rows j+1..j+5 (10 loads) may stay in flight ----
    asm volatile("s_waitcnt vmcnt(10)" ::: "memory");

    // ---- horizontal 11-tap conv of p,t,p^2,t^2,pt + vertical scatter ----
    const int rgj = r0 - 5 + j;
    if (rgj >= 0 && rgj < IMG_H) {        // wave-uniform (r0, j uniform)
        const int sR = j & (RING - 1);
        const float* Lb = &B[sR][lane + 3];       // one base -> ds_read2
        v2f h01 = {0.f, 0.f};                     // {hp, ht}
        v2f h23 = {0.f, 0.f};                     // {hpp, htt}
        float hpt = 0.f;
        #pragma unroll
        for (int k = 0; k < 11; ++k) {
            const float w = G[k];
            const v2f wv = {w, w};
            v2f v;
            v.x = Lb[k];                          // p
            v.y = Lb[k + 80];                     // t   (read2 candidate)
            h01 = __builtin_elementwise_fma(wv, v, h01);     // pk_fma
            const v2f wab = wv * v;                          // pk_mul {wx,wy}
            h23 = __builtin_elementwise_fma(wab, v, h23);    // pk_fma
            hpt = fmaf(wab.x, v.y, hpt);                     // scalar fma
        }
        // vertical scatter: row j feeds outputs l = j-10..j, slot = l%11
#define SCAT(s) { constexpr int m = ((s) - PH + 21) % 11;                    \
                  constexpr float w = G[10 - m];                             \
                  const v2f wv = {w, w};                                     \
                  acc01[s] = __builtin_elementwise_fma(wv, h01, acc01[s]);   \
                  acc23[s] = __builtin_elementwise_fma(wv, h23, acc23[s]);   \
                  accpt[s] = fmaf(w, hpt, accpt[s]); }
        SCAT(0) SCAT(1) SCAT(2) SCAT(3) SCAT(4) SCAT(5)
        SCAT(6) SCAT(7) SCAT(8) SCAT(9) SCAT(10)
#undef SCAT
    }
    // (row-OOB: conv of zero rows contributes zero -> skip is identical.)

    // ---- emit completed output row l = j-10 (slot (PH+1)%11), then reset ----
    constexpr int SE = (PH + 1) % 11;
    const int l = j - 10;
    if (l >= 0 && l < TH) {                       // wave-uniform branch
        const float mp = acc01[SE].x, mt = acc01[SE].y;
        const float mpp = mp * mp, mtt = mt * mt, mpt = mp * mt;
        const float sp  = acc23[SE].x - mpp;
        const float st  = acc23[SE].y - mtt;
        const float spt = accpt[SE]   - mpt;
        const float num = (2.f * mpt + SSIM_C1) * (2.f * spt + SSIM_C2);
        const float den = (mpp + mtt + SSIM_C1) * (sp + st + SSIM_C2);
        lsum += num * __builtin_amdgcn_rcpf(den); // den >= C1*C2 > 0
    }
    acc01[SE] = (v2f){0.f, 0.f};
    acc23[SE] = (v2f){0.f, 0.f};
    accpt[SE] = 0.f;
}

__global__ __launch_bounds__(256, 4) void ssim_main(const float* __restrict__ pred,
                                                    const float* __restrict__ targ,
                                                    float* __restrict__ ws) {
    __shared__ float B[4][RING][LROW];    // [wave][slot][p|t]  = 20.0 KB
    __shared__ float wsum[4];

    const int tid  = threadIdx.x;
    const int lane = tid & 63;
    const int wid  = tid >> 6;

    // 6144 tiles = 8 col-strips x 8 row-bands x 96 planes; 4 waves/block.
    const int gt    = __builtin_amdgcn_readfirstlane(blockIdx.x * 4 + wid);
    const int c0    = (gt & 7) * TH;
    const int r0    = ((gt >> 3) & 7) * TH;
    const int plane = gt >> 6;
    // Window base: column c0-8 (16B-aligned since c0%64==0).
    const float* pplw = pred + (size_t)plane * (IMG_H * IMG_W) + (c0 - 8);
    const float* tplw = targ + (size_t)plane * (IMG_H * IMG_W) + (c0 - 8);

    float (*W)[LROW] = B[wid];

    // Lane covers window cols [4*lane, 4*lane+3] = global [c0-8+4*lane, +3].
    const int  lane4 = lane * 4;
    const int  gc0   = c0 - 8 + lane4;
    const bool lv    = (lane < 20) && (gc0 >= 0) && (gc0 <= IMG_W - 4);

    // Pre-zero LDS words of permanently masked lanes (edge strips only):
    // gload_lds never touches them, so they stay zero all kernel.
    if (lane < 20 && !lv) {
        #pragma unroll
        for (int s = 0; s < RING; ++s) {
            #pragma unroll
            for (int w = 0; w < 4; ++w) {
                W[s][lane4 + w]      = 0.f;       // p section
                W[s][80 + lane4 + w] = 0.f;       // t section
            }
        }
    }

    // Prologue: issue rows j=0..4 (global rows r0-5..r0-1, clamped) into
    // ring slots 0..4 = 10 VMEM ops.
    #pragma unroll
    for (int r = 0; r < 5; ++r) {
        const int rg  = max(r0 - 5 + r, 0);       // top clamp only (r0<=448)
        const float* ps = pplw + (size_t)rg * IMG_W + lane4;
        const float* ts = tplw + (size_t)rg * IMG_W + lane4;
        if (lv) {
            gload16(ps, &W[r][0]);
            gload16(ts, &W[r][80]);
        }
    }

    v2f   acc01[11];
    v2f   acc23[11];
    float accpt[11];
    #pragma unroll
    for (int s = 0; s < 11; ++s) {
        acc01[s] = (v2f){0.f, 0.f};
        acc23[s] = (v2f){0.f, 0.f};
        accpt[s] = 0.f;
    }

    float lsum = 0.f;

    for (int chunk = 0; chunk < NCHUNK; ++chunk) {
        const int j0 = chunk * 11;
#define P(n) phase<n>(pplw, tplw, r0, j0, lane4, W, lane, lv, \
                      acc01, acc23, accpt, lsum);
        P(0) P(1) P(2) P(3) P(4) P(5) P(6) P(7) P(8) P(9) P(10)
#undef P
    }

    // wave reduce -> one plain store per block into the workspace
    #pragma unroll
    for (int off = 32; off > 0; off >>= 1) lsum += __shfl_down(lsum, off);
    if (lane == 0) wsum[wid] = lsum;
    __syncthreads();
    if (tid == 0) ws[blockIdx.x] = wsum[0] + wsum[1] + wsum[2] + wsum[3];
}

__global__ __launch_bounds__(256) void ssim_finalize(const float* __restrict__ ws,
                                                     float* __restrict__ out) {
    __shared__ float wsum[4];
    const int tid  = threadIdx.x;
    const int lane = tid & 63;
    const int wid  = tid >> 6;
    float s = 0.f;
    #pragma unroll
    for (int i = 0; i < 6; ++i) s += ws[tid + 256 * i];   // 1536 = 6*256
    #pragma unroll
    for (int off = 32; off > 0; off >>= 1) s += __shfl_down(s, off);
    if (lane == 0) wsum[wid] = s;
    __syncthreads();
    if (tid == 0) {
        const float tot = wsum[0] + wsum[1] + wsum[2] + wsum[3];
        out[0] = 1.0f - tot * (1.0f / 25165824.0f);  // 1 - sum/(32*3*512*512)
    }
}

extern "C" void kernel_launch(void* const* d_in, const int* in_sizes, int n_in,
                              void* d_out, int out_size, void* d_ws, size_t ws_size,
                              hipStream_t stream) {
    (void)in_sizes; (void)n_in; (void)out_size; (void)ws_size;
    const float* pred = (const float*)d_in[0];
    const float* targ = (const float*)d_in[1];
    float* ws  = (float*)d_ws;          // 1536 floats of scratch
    float* out = (float*)d_out;

    ssim_main<<<dim3(1536), 256, 0, stream>>>(pred, targ, ws);
    ssim_finalize<<<1, 256, 0, stream>>>(ws, out);
}